// Round 10
// baseline (322.649 us; speedup 1.0000x reference)
//
#include <hip/hip_runtime.h>
#include <math.h>

// Problem constants
#define B_ 2
#define T_ 2048
#define C_ 1024
#define H_ 16
#define HD_ 64

typedef __bf16 bf16;
typedef __bf16 bf8v __attribute__((ext_vector_type(8)));
typedef __bf16 bf4v __attribute__((ext_vector_type(4)));
typedef float  f4v  __attribute__((ext_vector_type(4)));

#define MFMA16(a,b,c) __builtin_amdgcn_mfma_f32_16x16x32_bf16((a),(b),(c),0,0,0)

typedef const __attribute__((address_space(1))) void* gas_ptr;
typedef __attribute__((address_space(3))) void*       las_ptr;

static __device__ __forceinline__ void gload_lds16(const void* g, void* l) {
  __builtin_amdgcn_global_load_lds((gas_ptr)g, (las_ptr)l, 16, 0, 0);
}

// ---------------- fused prep: f32->bf16 convert + both weight transposes ----------------
// blocks [0,2048): convert x; [2048,5120): Wattn transpose; [5120,6144): Wproj transpose
__global__ void k_prep(const float* __restrict__ x, bf16* __restrict__ xb,
                       const float* __restrict__ Wattn, bf16* __restrict__ WabT,
                       const float* __restrict__ Wproj, bf16* __restrict__ WpbT) {
  __shared__ float tbuf[32][33];
  int blk = blockIdx.x, tid = threadIdx.x;
  if (blk < 2048) {
    const int n4 = (B_ * T_ * C_) / 4;
    for (int i = blk * 256 + tid; i < n4; i += 2048 * 256) {
      float4 v = reinterpret_cast<const float4*>(x)[i];
      bf4v o; o[0] = (bf16)v.x; o[1] = (bf16)v.y; o[2] = (bf16)v.z; o[3] = (bf16)v.w;
      reinterpret_cast<bf4v*>(xb)[i] = o;
    }
    return;
  }
  const float* in; bf16* outb; int R, Cc, c0, r0;
  if (blk < 5120) {
    int b2 = blk - 2048; in = Wattn; outb = WabT; R = 1024; Cc = 3072;
    c0 = (b2 % 96) * 32; r0 = (b2 / 96) * 32;
  } else {
    int b3 = blk - 5120; in = Wproj; outb = WpbT; R = 1024; Cc = 1024;
    c0 = (b3 & 31) * 32; r0 = (b3 >> 5) * 32;
  }
  int tx = tid & 31, ty = tid >> 5;
  for (int i = ty; i < 32; i += 8)
    tbuf[i][tx] = in[(size_t)(r0 + i) * Cc + c0 + tx];
  __syncthreads();
  for (int i = ty; i < 32; i += 8)
    outb[(size_t)(c0 + i) * R + r0 + tx] = (bf16)tbuf[tx][i];
}

// ---------------- per-batch fractional positions (histogram + cumsum) ----------------
__global__ void k_positions(const int* __restrict__ tok, float* __restrict__ partial) {
  __shared__ float cnt[2048];
  __shared__ float tsum[256];
  int b = blockIdx.x, tid = threadIdx.x;
  const int* ti = tok + b * 2048;
  for (int i = tid; i < 2048; i += 256) cnt[i] = 0.f;
  __syncthreads();
  for (int i = tid; i < 2048; i += 256) atomicAdd(&cnt[ti[i]], 1.f);
  __syncthreads();
  float loc[8]; float s = 0.f;
#pragma unroll
  for (int j = 0; j < 8; ++j) { loc[j] = 1.f / cnt[ti[tid * 8 + j]]; s += loc[j]; }
  tsum[tid] = s;
  __syncthreads();
  for (int off = 1; off < 256; off <<= 1) {
    float v = (tid >= off) ? tsum[tid - off] : 0.f;
    __syncthreads();
    tsum[tid] += v;
    __syncthreads();
  }
  float run = (tid > 0) ? tsum[tid - 1] : 0.f;
  float* po = partial + b * 2048;
#pragma unroll
  for (int j = 0; j < 8; ++j) { run += loc[j]; po[tid * 8 + j] = run; }
}

// ---------------- cos/sin tables + gathered padding mask ----------------
__global__ void k_tables(const float* __restrict__ partial, const float* __restrict__ pad,
                         const int* __restrict__ tok,
                         float* __restrict__ ctab, float* __restrict__ stab, float* __restrict__ pmg) {
  int i = blockIdx.x * blockDim.x + threadIdx.x;
  if (i >= B_ * T_) return;
  int b = i >> 11;
  float p = partial[i];
  for (int d = 0; d < 32; ++d) {
    float inv = exp2f((float)d * -0.41524101186092028f);  // log2(10000)/32
    float ang = p * inv;
    float sn, cs; sincosf(ang, &sn, &cs);
    ctab[i * 32 + d] = cs; stab[i * 32 + d] = sn;
  }
  pmg[i] = pad[b * 2048 + tok[i]];
}

// ---------------- shared GEMM core: single-barrier double-buffered K-loop ----------------
static __device__ __forceinline__ void gemm_core(const bf16* __restrict__ A, const bf16* __restrict__ BT,
                                                 int K, int bm0, int bn0,
                                                 f4v (&acc)[4][4],
                                                 bf16 (*As)[128 * 32], bf16 (*Bs)[128 * 32]) {
  int tid = threadIdx.x;
  int w = tid >> 6, l = tid & 63;
  int wr = w >> 1, wc = w & 1;
  int lg = l >> 4, lr = l & 15;
  int srow = l >> 2;            // row within 16-row staging chunk
  int scol = (l & 3) * 8;       // element col within BK
  auto STAGE = [&](int buf, int k0) {
#pragma unroll
    for (int i = 0; i < 2; ++i) {
      int rblk = w * 32 + i * 16;
      gload_lds16(A  + (size_t)(bm0 + rblk + srow) * K + k0 + scol, As[buf] + rblk * 32);
      gload_lds16(BT + (size_t)(bn0 + rblk + srow) * K + k0 + scol, Bs[buf] + rblk * 32);
    }
  };
  STAGE(0, 0);
  __syncthreads();
  int cur = 0;
  for (int k0 = 0; k0 < K; k0 += 32) {
    if (k0 + 32 < K) STAGE(cur ^ 1, k0 + 32);
    bf8v af[4], bb[4];
#pragma unroll
    for (int fm = 0; fm < 4; ++fm)
      af[fm] = *reinterpret_cast<const bf8v*>(As[cur] + (wr * 64 + fm * 16 + lr) * 32 + lg * 8);
#pragma unroll
    for (int fn = 0; fn < 4; ++fn)
      bb[fn] = *reinterpret_cast<const bf8v*>(Bs[cur] + (wc * 64 + fn * 16 + lr) * 32 + lg * 8);
#pragma unroll
    for (int fm = 0; fm < 4; ++fm)
#pragma unroll
      for (int fn = 0; fn < 4; ++fn)
        acc[fm][fn] = MFMA16(af[fm], bb[fn], acc[fm][fn]);
    __syncthreads();
    cur ^= 1;
  }
}

// ---------------- fused QKV GEMM + RoPE/fork/v-scale epilogue, coalesced stores ----------------
// After the K-loop's final barrier, As/Bs (32KB) are dead; each wave uses its private
// 8KB slice as a restage buffer so every global store is a full 128B line (Q/K) or
// full 64B sectors (V^T). No extra barriers (per-wave buffers).
__global__ __launch_bounds__(256) void k_gemm_qkv(const bf16* __restrict__ A, const bf16* __restrict__ BT,
                                                  const float* __restrict__ bias,
                                                  const float* __restrict__ ctab, const float* __restrict__ stab,
                                                  const float* __restrict__ cum,
                                                  bf16* __restrict__ Qh, bf16* __restrict__ Kh,
                                                  bf16* __restrict__ VhT) {
  __shared__ bf16 As[2][128 * 32];
  __shared__ bf16 Bs[2][128 * 32];
  int tid = threadIdx.x;
  int w = tid >> 6, l = tid & 63;
  int wr = w >> 1, wc = w & 1;
  int lg = l >> 4, lr = l & 15;
  int bm0 = blockIdx.y * 128, bn0 = blockIdx.x * 128;
  f4v acc[4][4] = {};
  gemm_core(A, BT, 1024, bm0, bn0, acc, As, Bs);
  // ---- epilogue (per-wave restage buffer over dead As/Bs) ----
  bf16* scr = reinterpret_cast<bf16*>(reinterpret_cast<char*>(&As[0][0]) + w * 8192);
  int type = bn0 >> 10;                      // 0=q, 1=k, 2=v
  int h = ((bn0 & 1023) >> 6) + wc;          // head for this wave's 64-col block
  int cbase = bn0 + wc * 64;
  int r0 = bm0 + wr * 64;                    // token base of wave's quadrant
  int b2 = r0 >> 11;
  float bs[4];
#pragma unroll
  for (int fn = 0; fn < 4; ++fn) bs[fn] = bias[cbase + fn * 16 + lr];
  if (type == 2) {
    // V: scale by exp(cum), restage TRANSPOSED in scr[64][40], store 64B rows
    size_t vbase = (size_t)(b2 * 16 + h) * 64 * 2048 + (r0 & 2047);
#pragma unroll
    for (int hp = 0; hp < 2; ++hp) {
#pragma unroll
      for (int fm2 = 0; fm2 < 2; ++fm2) {
        int fm = hp * 2 + fm2;
        int rbase = r0 + fm * 16 + lg * 4;
        float ve[4];
#pragma unroll
        for (int j = 0; j < 4; ++j) ve[j] = __expf(cum[rbase + j]);
#pragma unroll
        for (int fn = 0; fn < 4; ++fn)
#pragma unroll
          for (int j = 0; j < 4; ++j)
            scr[(fn * 16 + lr) * 40 + fm2 * 16 + lg * 4 + j] = (bf16)((acc[fm][fn][j] + bs[fn]) * ve[j]);
      }
#pragma unroll
      for (int i = 0; i < 4; ++i) {
        int d = (l >> 2) + i * 16, c = l & 3;
        bf8v vv = *reinterpret_cast<const bf8v*>(scr + d * 40 + c * 8);
        *reinterpret_cast<bf8v*>(VhT + vbase + (size_t)d * 2048 + hp * 32 + c * 8) = vv;
      }
    }
  } else {
    // Q/K: RoPE + fork, restage in scr[32][72], store 128B rows
    bf16* Out = (type == 0) ? Qh : Kh;
    size_t qbase = ((size_t)(b2 * 16 + h) * 2048 + (r0 & 2047)) * 64;
#pragma unroll
    for (int hp = 0; hp < 2; ++hp) {
#pragma unroll
      for (int fm2 = 0; fm2 < 2; ++fm2) {
        int fm = hp * 2 + fm2;
#pragma unroll
        for (int j = 0; j < 4; ++j) {
          int r = r0 + fm * 16 + lg * 4 + j;
          float cumv = cum[r];
          float cs0 = ctab[r * 32 + lr],      sn0 = stab[r * 32 + lr];
          float cs1 = ctab[r * 32 + 16 + lr], sn1 = stab[r * 32 + 16 + lr];
#pragma unroll
          for (int fn = 0; fn < 4; ++fn) {
            int d = fn * 16 + lr;
            float val = acc[fm][fn][j] + bs[fn];
            float par = acc[fm][fn ^ 2][j] + bs[fn ^ 2];
            float cs = (fn & 1) ? cs1 : cs0, sn = (fn & 1) ? sn1 : sn0;
            float rot = val * cs + ((fn < 2) ? -par : par) * sn;
            if (d == 63) rot = (type == 0) ? 1.f : cumv;
            scr[(fm2 * 16 + lg * 4 + j) * 72 + d] = (bf16)rot;
          }
        }
      }
#pragma unroll
      for (int i = 0; i < 4; ++i) {
        int gr = (l >> 3) + i * 8, c = l & 7;
        bf8v vv = *reinterpret_cast<const bf8v*>(scr + gr * 72 + c * 8);
        *reinterpret_cast<bf8v*>(Out + qbase + (size_t)(hp * 32 + gr) * 64 + c * 8) = vv;
      }
    }
  }
}

// ---------------- plain GEMM: C[M,N] = A[M,K] @ BT[N,K]^T + bias (f32 out) ----------------
__global__ __launch_bounds__(256) void k_gemm_bt(const bf16* __restrict__ A, const bf16* __restrict__ BT,
                                                 const float* __restrict__ bias, float* __restrict__ Cout,
                                                 int M, int N, int K) {
  __shared__ bf16 As[2][128 * 32];
  __shared__ bf16 Bs[2][128 * 32];
  int tid = threadIdx.x;
  int w = tid >> 6, l = tid & 63;
  int wr = w >> 1, wc = w & 1;
  int lg = l >> 4, lr = l & 15;
  int bm0 = blockIdx.y * 128, bn0 = blockIdx.x * 128;
  f4v acc[4][4] = {};
  gemm_core(A, BT, K, bm0, bn0, acc, As, Bs);
  int r0 = bm0 + wr * 64, c0 = bn0 + wc * 64;
#pragma unroll
  for (int fm = 0; fm < 4; ++fm)
#pragma unroll
    for (int fn = 0; fn < 4; ++fn)
#pragma unroll
      for (int j = 0; j < 4; ++j) {
        int r = r0 + fm * 16 + lg * 4 + j, c = c0 + fn * 16 + lr;
        Cout[(size_t)r * N + c] = acc[fm][fn][j] + bias[c];
      }
}

// ---------------- flash attention: NO K/V LDS staging (L2/L3-resident) ----------------
// K+V per head = 512KB (L2-scale), whole tensor 16MB (L3-resident). Fragments are
// read directly from global (16B/lane); V prefetched into regs before softmax.
// LDS = Pl only (9216B) -> occupancy is VGPR-bound (~4-5 waves/SIMD), no barriers.
__global__ __launch_bounds__(256) void k_attn(const bf16* __restrict__ Qh, const bf16* __restrict__ Kh,
                                              const bf16* __restrict__ VhT, const float* __restrict__ pmg,
                                              bf16* __restrict__ Y) {
  __shared__ bf16 Pl[4][16][72];    // per-wave P re-fragment
  int bid = blockIdx.x;
  int qt = 31 - (bid >> 5);
  int bh = bid & 31;
  int b = bh >> 4;
  int tid = threadIdx.x, w = tid >> 6, l = tid & 63;
  int lg = l >> 4, lr = l & 15;
  const bf16* Kbase = Kh  + (size_t)bh * 2048 * 64;
  const bf16* Vbase = VhT + (size_t)bh * 64 * 2048;
  int qrow_f = qt * 64 + w * 16 + lr;
  bf8v qf0 = *reinterpret_cast<const bf8v*>(Qh + (size_t)bh * 2048 * 64 + (size_t)qrow_f * 64 + lg * 8);
  bf8v qf1 = *reinterpret_cast<const bf8v*>(Qh + (size_t)bh * 2048 * 64 + (size_t)qrow_f * 64 + 32 + lg * 8);
  float radd[4];
#pragma unroll
  for (int j = 0; j < 4; ++j) {
    float pq = pmg[b * 2048 + qt * 64 + w * 16 + lg * 4 + j];
    radd[j] = (pq != 0.f) ? 0.f : -1e30f;
  }
  float m_run[4] = {-INFINITY, -INFINITY, -INFINITY, -INFINITY};
  float l_run[4] = {0.f, 0.f, 0.f, 0.f};
  f4v o_acc[4] = {};
  for (int kt = 0; kt <= qt; ++kt) {
    // QK^T: K fragments direct from global
    f4v sa[4] = {};
    __builtin_amdgcn_s_setprio(1);
#pragma unroll
    for (int nf = 0; nf < 4; ++nf) {
      const bf16* kr = Kbase + (size_t)(kt * 64 + nf * 16 + lr) * 64;
      bf8v kf0 = *reinterpret_cast<const bf8v*>(kr + lg * 8);
      bf8v kf1 = *reinterpret_cast<const bf8v*>(kr + 32 + lg * 8);
      sa[nf] = MFMA16(qf0, kf0, sa[nf]);
      sa[nf] = MFMA16(qf1, kf1, sa[nf]);
    }
    __builtin_amdgcn_s_setprio(0);
    // V fragment prefetch (independent of softmax -> latency hides under it)
    bf8v vf[4][2];
#pragma unroll
    for (int df = 0; df < 4; ++df) {
      const bf16* vr = Vbase + (size_t)(df * 16 + lr) * 2048 + kt * 64;
      vf[df][0] = *reinterpret_cast<const bf8v*>(vr + lg * 8);
      vf[df][1] = *reinterpret_cast<const bf8v*>(vr + 32 + lg * 8);
    }
    // mask + scale (additive -1e30 masks; causal compare only on diagonal tile)
    float pv[4][4];
    float mx[4];
#pragma unroll
    for (int nf = 0; nf < 4; ++nf) {
      int kcol = kt * 64 + nf * 16 + lr;
      float pk = pmg[b * 2048 + kcol];
      float cm = (pk != 0.f) ? 0.f : -1e30f;
#pragma unroll
      for (int j = 0; j < 4; ++j) {
        float add = cm + radd[j];
        if (kt == qt) {
          int qrow = qt * 64 + w * 16 + lg * 4 + j;
          if (kcol > qrow) add = -1e30f;
        }
        float s = fmaf(sa[nf][j], 0.125f, add);
        pv[nf][j] = s;
        mx[j] = (nf == 0) ? s : fmaxf(mx[j], s);
      }
    }
    for (int off = 1; off < 16; off <<= 1)
#pragma unroll
      for (int j = 0; j < 4; ++j) mx[j] = fmaxf(mx[j], __shfl_xor(mx[j], off));
    bool grow = false;
#pragma unroll
    for (int j = 0; j < 4; ++j) grow |= (mx[j] > m_run[j] + 8.f);
    if (__any(grow)) {
#pragma unroll
      for (int j = 0; j < 4; ++j) {
        float mnew = fmaxf(m_run[j], mx[j]);
        float scl = __expf(m_run[j] - mnew);
        m_run[j] = mnew;
        l_run[j] *= scl;
#pragma unroll
        for (int df = 0; df < 4; ++df) o_acc[df][j] *= scl;
      }
    }
    float rs[4] = {0.f, 0.f, 0.f, 0.f};
#pragma unroll
    for (int nf = 0; nf < 4; ++nf)
#pragma unroll
      for (int j = 0; j < 4; ++j) {
        float p = __expf(pv[nf][j] - m_run[j]);
        pv[nf][j] = p;
        rs[j] += p;
      }
    for (int off = 1; off < 16; off <<= 1)
#pragma unroll
      for (int j = 0; j < 4; ++j) rs[j] += __shfl_xor(rs[j], off);
#pragma unroll
    for (int j = 0; j < 4; ++j) l_run[j] += rs[j];
    // P -> per-wave LDS re-fragment (same-wave dep, no barrier)
#pragma unroll
    for (int nf = 0; nf < 4; ++nf)
#pragma unroll
      for (int j = 0; j < 4; ++j)
        Pl[w][lg * 4 + j][nf * 16 + lr] = (bf16)pv[nf][j];
    bf8v pa0 = *reinterpret_cast<const bf8v*>(&Pl[w][lr][lg * 8]);
    bf8v pa1 = *reinterpret_cast<const bf8v*>(&Pl[w][lr][32 + lg * 8]);
    __builtin_amdgcn_s_setprio(1);
#pragma unroll
    for (int df = 0; df < 4; ++df) {
      o_acc[df] = MFMA16(pa0, vf[df][0], o_acc[df]);
      o_acc[df] = MFMA16(pa1, vf[df][1], o_acc[df]);
    }
    __builtin_amdgcn_s_setprio(0);
  }
  int h = bh & 15;
#pragma unroll
  for (int j = 0; j < 4; ++j) {
    float inv = 1.f / l_run[j];
    int trow = qt * 64 + w * 16 + lg * 4 + j;
#pragma unroll
    for (int df = 0; df < 4; ++df)
      Y[((size_t)(b * 2048 + trow) * 16 + h) * 64 + df * 16 + lr] = (bf16)(o_acc[df][j] * inv);
  }
}

// ---------------- launcher ----------------
// ws layout (bytes) — total 44,040,192 B (42 MiB):
//   partial @ 0          : 16384
//   ctab    @ 16384      : 524288
//   stab    @ 540672     : 524288
//   pmg     @ 1064960    : 16384
//   WabT    @ 2097152    : 6291456   (3072x1024 bf16)
//   WpbT    @ 8388608    : 2097152   (1024x1024 bf16)
//   xb      @ 10485760   : 8388608   (4096x1024 bf16) -- reused as Ybf after qkv GEMM
//   Qh      @ 18874368   : 8388608   ([B,H,T,64] bf16)
//   Kh      @ 27262976   : 8388608   ([B,H,T,64] bf16)
//   VhT     @ 35651584   : 8388608   ([B*H,64,T] bf16 — V transposed)
extern "C" void kernel_launch(void* const* d_in, const int* in_sizes, int n_in,
                              void* d_out, int out_size, void* d_ws, size_t ws_size,
                              hipStream_t stream) {
  const float* x     = (const float*)d_in[0];
  const float* cum   = (const float*)d_in[1];
  const float* pad   = (const float*)d_in[2];
  const float* Wattn = (const float*)d_in[3];
  const float* battn = (const float*)d_in[4];
  const float* Wproj = (const float*)d_in[5];
  const float* bproj = (const float*)d_in[6];
  const int*   tok   = (const int*)d_in[7];
  float* out = (float*)d_out;
  char* ws = (char*)d_ws;

  float* partial = (float*)(ws);
  float* ctab    = (float*)(ws + 16384);
  float* stab    = (float*)(ws + 540672);
  float* pmg     = (float*)(ws + 1064960);
  bf16*  WabT    = (bf16*)(ws + 2097152);
  bf16*  WpbT    = (bf16*)(ws + 8388608);
  bf16*  xb      = (bf16*)(ws + 10485760);
  bf16*  Qh      = (bf16*)(ws + 18874368);
  bf16*  Kh      = (bf16*)(ws + 27262976);
  bf16*  VhT     = (bf16*)(ws + 35651584);
  bf16*  Ybf     = xb;  // xb dead after qkv GEMM

  k_prep<<<6144, 256, 0, stream>>>(x, xb, Wattn, WabT, Wproj, WpbT);
  k_positions<<<2, 256, 0, stream>>>(tok, partial);
  k_tables<<<16, 256, 0, stream>>>(partial, pad, tok, ctab, stab, pmg);
  k_gemm_qkv<<<dim3(24, 32), 256, 0, stream>>>(xb, WabT, battn, ctab, stab, cum, Qh, Kh, VhT);
  k_attn<<<1024, 256, 0, stream>>>(Qh, Kh, VhT, pmg, Ybf);
  k_gemm_bt<<<dim3(8, 32), 256, 0, stream>>>(Ybf, WpbT, bproj, out, 4096, 1024, 1024);
}